// Round 6
// baseline (271.460 us; speedup 1.0000x reference)
//
#include <hip/hip_runtime.h>
#include <hip/hip_bf16.h>
#include <math.h>

typedef __hip_bfloat16 bf16;
typedef __attribute__((ext_vector_type(4))) float f32x4;
typedef __attribute__((ext_vector_type(8))) short s16x8;

typedef const __attribute__((address_space(1))) void gvoid_t;
typedef __attribute__((address_space(3))) void lvoid_t;

__device__ __forceinline__ void gload16(const void* g, void* l) {
  // async global->LDS, 16B/lane; LDS dest is wave-uniform base + lane*16
  __builtin_amdgcn_global_load_lds((gvoid_t*)g, (lvoid_t*)l, 16, 0, 0);
}
__device__ __forceinline__ unsigned short f2b(float f) {
  bf16 h = __float2bfloat16(f);
  return *(unsigned short*)&h;
}

// ---------------- prep: x = concat(patches, positions) -> bf16 [16384][832]
__global__ __launch_bounds__(256) void prep_x(const float* __restrict__ patches,
                                              const float* __restrict__ positions,
                                              bf16* __restrict__ xb) {
  const int c = threadIdx.x;
  const bool lo = (c < 192);
  const bool hi = (c >= 192) && (c < 208);
  if (!(lo || hi)) return;
  const int dst = lo ? (c * 4) : (768 + (c - 192) * 4);
  #pragma unroll
  for (int rr = 0; rr < 8; ++rr) {
    const long long row = (long long)blockIdx.x * 8 + rr;
    const float* src = lo ? (patches + row * 768 + c * 4)
                          : (positions + row * 64 + (c - 192) * 4);
    float4 v = *(const float4*)src;
    uint2 w;
    w.x = (unsigned int)f2b(v.x) | ((unsigned int)f2b(v.y) << 16);
    w.y = (unsigned int)f2b(v.z) | ((unsigned int)f2b(v.w) << 16);
    *(uint2*)(xb + row * 832 + dst) = w;
  }
}

// ---------------- prep: Wt[z*512+n][k] = W_z[k][n] bf16 (832x512 -> 512x832)
__global__ __launch_bounds__(256) void prep_w(const float* __restrict__ Wq,
                                              const float* __restrict__ Wk,
                                              const float* __restrict__ Wv,
                                              bf16* __restrict__ Wt) {
  __shared__ float tile[32][33];
  const int z = blockIdx.z;
  const float* W = (z == 0) ? Wq : (z == 1) ? Wk : Wv;
  bf16* T = Wt + (long long)z * 512 * 832;
  const int n0 = blockIdx.x * 32;
  const int k0 = blockIdx.y * 32;
  const int tx = threadIdx.x, ty = threadIdx.y;  // (32,8)
  #pragma unroll
  for (int i = 0; i < 32; i += 8)
    tile[ty + i][tx] = W[(long long)(k0 + ty + i) * 512 + n0 + tx];
  __syncthreads();
  #pragma unroll
  for (int i = 0; i < 32; i += 8)
    T[(long long)(n0 + ty + i) * 832 + k0 + tx] = __float2bfloat16(tile[tx][ty + i]);
}

// ================ shared counted-vmcnt template pieces (HW-verified) ========
#define VMW8  asm volatile("s_waitcnt vmcnt(8)" ::: "memory")
#define VMW10 asm volatile("s_waitcnt vmcnt(10)" ::: "memory")
#define PBAR do { __builtin_amdgcn_s_barrier(); __builtin_amdgcn_sched_barrier(0); } while (0)

__device__ __forceinline__ void stage_half(const bf16* src, char* lds, int stride) {
  gload16(src, lds);                       // rows r..r+63 of the 128-row half
  gload16(src + 64 * stride, lds + 8192);  // rows r+64..r+127
}
__device__ __forceinline__ void lda4(const bf16* base, int rowbase, int llo,
                                     int xk0, int xk1, s16x8 af[4][2]) {
  #pragma unroll
  for (int mf = 0; mf < 4; mf++) {
    const bf16* p = base + (rowbase + mf * 16 + llo) * 64;
    af[mf][0] = *(const s16x8*)(p + xk0);
    af[mf][1] = *(const s16x8*)(p + xk1);
  }
}
__device__ __forceinline__ void ldb2(const bf16* base, int rowbase, int llo,
                                     int xk0, int xk1, s16x8 bfr[2][2]) {
  #pragma unroll
  for (int nf = 0; nf < 2; nf++) {
    const bf16* p = base + (rowbase + nf * 16 + llo) * 64;
    bfr[nf][0] = *(const s16x8*)(p + xk0);
    bfr[nf][1] = *(const s16x8*)(p + xk1);
  }
}
__device__ __forceinline__ void mma16(f32x4 acc[4][2], s16x8 af[4][2],
                                      s16x8 bfr[2][2]) {
  __builtin_amdgcn_s_setprio(1);
  #pragma unroll
  for (int mf = 0; mf < 4; mf++)
    #pragma unroll
    for (int nf = 0; nf < 2; nf++) {
      acc[mf][nf] = __builtin_amdgcn_mfma_f32_16x16x32_bf16(
          af[mf][0], bfr[nf][0], acc[mf][nf], 0, 0, 0);
      acc[mf][nf] = __builtin_amdgcn_mfma_f32_16x16x32_bf16(
          af[mf][1], bfr[nf][1], acc[mf][nf], 0, 0, 0);
    }
  __builtin_amdgcn_s_setprio(0);
}

// ---------------- fused QKV projection: [16384,832] x [1536,832]^T
// NEW: clone of the HW-verified R4-pv TRIPLE-buffered schedule (stage
// distance = 2 tiles, waits VMW10/VMW8, >=8 loads in flight, consume
// distance ~2.5 phases = ~3000 cyc > HBM latency; fixes R5's exposed-latency
// stall where dbuf-A forced issue->wait cover of only ~500 cyc).
// Geometry: 256x128 tile -> 64x12 = 768 blocks = 3 EXACT rounds (768%8==0).
// LDS = 3*32 (A) + 3*16 (B) = 144 KB. Per tile: {a0,b} staged at Pa,
// {a1} at Pb, targeting buf (u+2)%3 (last read at tile u-1 -> WAR >= 2
// barriers). K=832 = 13 tiles: 4x3 main loop + tail tile 12 (clamped dup
// stages into dead buffers, final vmcnt(0) drain).
#define QKV_TILE(c, cs, kstage)                                             \
  do {                                                                      \
    /* Pa: qr=0 */                                                          \
    lda4(As3[c], wm * 64, llo, xk0, xk1, af);                               \
    ldb2(Bs3[c], wn * 32, llo, xk0, xk1, bfr);                              \
    stage_half(sA + (kstage), (char*)As3[cs] + wofs, 832);                  \
    stage_half(sB + (kstage), (char*)Bs3[cs] + wofs, 832);                  \
    VMW10; PBAR;                                                            \
    mma16(acc[0], af, bfr);                                                 \
    /* Pb: qr=1 (B frags reused from registers) */                          \
    lda4(As3[c], 128 + wm * 64, llo, xk0, xk1, af);                         \
    stage_half(sA + 128 * 832 + (kstage), (char*)As3[cs] + 16384 + wofs,    \
               832);                                                        \
    VMW8; PBAR;                                                             \
    mma16(acc[1], af, bfr);                                                 \
  } while (0)

__global__ __launch_bounds__(512, 2) void gemm_qkv(
    const bf16* __restrict__ xb, const bf16* __restrict__ Wt,
    const float* __restrict__ bq, const float* __restrict__ bk,
    const float* __restrict__ bv,
    bf16* __restrict__ qk, bf16* __restrict__ vt) {
  __shared__ bf16 As3[3][256 * 64];  // 32 KB each
  __shared__ bf16 Bs3[3][128 * 64];  // 16 KB each (total 144 KB)
  const int tid = threadIdx.x;
  const int wave = tid >> 6, lane = tid & 63;
  const int llo = lane & 15, lhi = lane >> 4;
  const int wm = wave >> 2, wn = wave & 3;  // 2 x 4 waves

  const unsigned int lin = blockIdx.x;      // 768 blocks (768%8==0, bijective)
  const unsigned int xcd = lin & 7u, idx = lin >> 3;  // idx 0..95
  const unsigned int g = xcd * 96u + idx;   // each XCD: 8 consecutive bm rows
  const int bm_t = (int)(g / 12u);          // 0..63
  const int bn_t = (int)(g - (unsigned)bm_t * 12u);  // 0..11
  const int row0 = bm_t * 256;
  const int col0 = bn_t * 128;
  const int z = col0 >> 9;                  // 128-col tiles never straddle z
  const int cc0 = col0 & 511;

  // staging: pre-swizzled global source, linear LDS dest (rule 21 pair)
  const int sr = tid >> 3;                        // 0..63
  const int kkofs = ((tid & 7) ^ (sr & 7)) << 3;  // element offset
  const bf16* sA = xb + (long long)(row0 + sr) * 832 + kkofs;
  const bf16* sB = Wt + (long long)(col0 + sr) * 832 + kkofs;
  const int wofs = wave * 1024;

  // read-side swizzled chunk offsets (elements), k0=0 and k0=32
  const int xk0 = ((lhi ^ (llo & 7)) << 3);
  const int xk1 = (((4 + lhi) ^ (llo & 7)) << 3);

  f32x4 acc[2][4][2] = {};  // [qr][mf][nf] — per-wave output 128x32
  s16x8 af[4][2], bfr[2][2];

  // prologue: tiles 0,1 fully staged = 12 loads, order a0,b,a1 per tile;
  // VMW8 retires a0(0),b(0) (Pa(0)'s reads) -> 8 in flight.
  stage_half(sA, (char*)As3[0] + wofs, 832);
  stage_half(sB, (char*)Bs3[0] + wofs, 832);
  stage_half(sA + 128 * 832, (char*)As3[0] + 16384 + wofs, 832);
  stage_half(sA + 64, (char*)As3[1] + wofs, 832);
  stage_half(sB + 64, (char*)Bs3[1] + wofs, 832);
  stage_half(sA + 128 * 832 + 64, (char*)As3[1] + 16384 + wofs, 832);
  VMW8; PBAR;

  for (int j = 0; j < 4; ++j) {        // tiles 3j..3j+2 (0..11)
    const int k2 = (j * 3 + 2) * 64;   // tile 3j   stages tile 3j+2 (real)
    const int k3 = (j * 3 + 3) * 64;   // tile 3j+1 stages tile 3j+3 (real)
    const int k4u = (j * 3 + 4) * 64;  // tile 3j+2 stages tile 3j+4
    const int k4 = (k4u <= 768) ? k4u : 768;  // j=3: clamp t13 -> dup of t12
    QKV_TILE(0, 2, k2);
    QKV_TILE(1, 0, k3);
    QKV_TILE(2, 1, k4);
  }
  // tail: tile 12 (buf0); clamped dup stages into buf2 (dead).
  QKV_TILE(0, 2, 768);

  asm volatile("s_waitcnt vmcnt(0)" ::: "memory");  // drain clamp dups

  // epilogue: C/D layout col=lane&15, row=(lane>>4)*4+reg; z block-uniform.
  if (z < 2) {
    const float* bias = z ? bk : bq;
    bf16* outp = qk + (long long)z * 16384 * 512;
    #pragma unroll
    for (int qr = 0; qr < 2; qr++)
      #pragma unroll
      for (int mf = 0; mf < 4; mf++)
        #pragma unroll
        for (int nf = 0; nf < 2; nf++) {
          const int c = cc0 + wn * 32 + nf * 16 + llo;
          const int grow0 = row0 + qr * 128 + wm * 64 + mf * 16 + lhi * 4;
          const float bb = bias[c];
          #pragma unroll
          for (int r = 0; r < 4; r++)
            outp[(long long)(grow0 + r) * 512 + c] =
                __float2bfloat16(acc[qr][mf][nf][r] + bb);
        }
  } else {
    #pragma unroll
    for (int qr = 0; qr < 2; qr++)
      #pragma unroll
      for (int mf = 0; mf < 4; mf++)
        #pragma unroll
        for (int nf = 0; nf < 2; nf++) {
          const int c = cc0 + wn * 32 + nf * 16 + llo;
          const int grow0 = row0 + qr * 128 + wm * 64 + mf * 16 + lhi * 4;
          const int b = grow0 >> 11, jj = grow0 & 2047;
          const float bb = bv[c];
          uint2 w;
          w.x = (unsigned int)f2b(acc[qr][mf][nf][0] + bb) |
                ((unsigned int)f2b(acc[qr][mf][nf][1] + bb) << 16);
          w.y = (unsigned int)f2b(acc[qr][mf][nf][2] + bb) |
                ((unsigned int)f2b(acc[qr][mf][nf][3] + bb) << 16);
          *(uint2*)(vt + (long long)b * 512 * 2048 + (long long)c * 2048 + jj) = w;
        }
  }
}
#undef QKV_TILE

// ---------------- scores+exp: 256x256 tile, 8 waves, 8-phase counted-vmcnt
// (passed rounds 1-5; unchanged)
__global__ __launch_bounds__(512, 2) void gemm_scores(const bf16* __restrict__ qk,
                                                      bf16* __restrict__ S,
                                                      float* __restrict__ rowsumP) {
  __shared__ bf16 As[2][256 * 64];
  __shared__ bf16 Bs[2][256 * 64];
  const int tid = threadIdx.x;
  const int wave = tid >> 6, lane = tid & 63;
  const int llo = lane & 15, lhi = lane >> 4;
  const int wm = wave >> 2, wn = wave & 3;  // 2 x 4 waves

  const unsigned int lin = blockIdx.x;  // 512 blocks
  const int b = (int)(lin & 7u);        // one batch per XCD (Q+K = 4MB = L2)
  const unsigned int idx = lin >> 3;    // 0..63
  const int row0 = (int)(idx >> 3) * 256;
  const int coltile = (int)(idx & 7u);
  const int col0 = coltile * 256;

  const bf16* Ab = qk + (long long)b * 2048 * 512;                           // Q
  const bf16* Bb = qk + (long long)16384 * 512 + (long long)b * 2048 * 512;  // K

  const int sr = tid >> 3;
  const int kkofs = ((tid & 7) ^ (sr & 7)) << 3;
  const bf16* sA = Ab + (long long)(row0 + sr) * 512 + kkofs;
  const bf16* sB = Bb + (long long)(col0 + sr) * 512 + kkofs;
  const int wofs = wave * 1024;

  const int xk0 = ((lhi ^ (llo & 7)) << 3);
  const int xk1 = (((4 + lhi) ^ (llo & 7)) << 3);

  f32x4 acc[2][2][4][2] = {};   // [qr][qc][mf][nf]
  s16x8 af[4][2], bf0[2][2], bf1[2][2];

  stage_half(sA, (char*)As[0] + wofs, 512);
  stage_half(sB, (char*)Bs[0] + wofs, 512);
  stage_half(sB + 128 * 512, (char*)Bs[0] + 16384 + wofs, 512);
  stage_half(sA + 128 * 512, (char*)As[0] + 16384 + wofs, 512);
  stage_half(sA + 64, (char*)As[1] + wofs, 512);
  stage_half(sB + 64, (char*)Bs[1] + wofs, 512);
  VMW8; PBAR;

  for (int i = 0; i < 4; ++i) {   // 2 K-tiles per iteration, K=512 -> 8 tiles
    const int kt1 = (2 * i + 1) * 64;
    const int kt2 = (2 * i + 2 < 8) ? (2 * i + 2) * 64 : 448;  // clamp tail
    const int kt3 = (2 * i + 3 < 8) ? (2 * i + 3) * 64 : 448;
    // P1
    lda4(As[0], wm * 64, llo, xk0, xk1, af);
    ldb2(Bs[0], wn * 32, llo, xk0, xk1, bf0);
    stage_half(sB + 128 * 512 + kt1, (char*)Bs[1] + 16384 + wofs, 512);
    VMW8; PBAR;
    mma16(acc[0][0], af, bf0);
    // P2
    ldb2(Bs[0], 128 + wn * 32, llo, xk0, xk1, bf1);
    stage_half(sA + 128 * 512 + kt1, (char*)As[1] + 16384 + wofs, 512);
    VMW8; PBAR;
    mma16(acc[0][1], af, bf1);
    // P3
    lda4(As[0], 128 + wm * 64, llo, xk0, xk1, af);
    stage_half(sA + kt2, (char*)As[0] + wofs, 512);
    PBAR;
    mma16(acc[1][0], af, bf0);
    // P4
    stage_half(sB + kt2, (char*)Bs[0] + wofs, 512);
    VMW8; PBAR;
    mma16(acc[1][1], af, bf1);
    // P5
    lda4(As[1], wm * 64, llo, xk0, xk1, af);
    ldb2(Bs[1], wn * 32, llo, xk0, xk1, bf0);
    stage_half(sB + 128 * 512 + kt2, (char*)Bs[0] + 16384 + wofs, 512);
    VMW8; PBAR;
    mma16(acc[0][0], af, bf0);
    // P6
    ldb2(Bs[1], 128 + wn * 32, llo, xk0, xk1, bf1);
    stage_half(sA + 128 * 512 + kt2, (char*)As[0] + 16384 + wofs, 512);
    VMW8; PBAR;
    mma16(acc[0][1], af, bf1);
    // P7
    lda4(As[1], 128 + wm * 64, llo, xk0, xk1, af);
    stage_half(sA + kt3, (char*)As[1] + wofs, 512);
    PBAR;
    mma16(acc[1][0], af, bf0);
    // P8
    stage_half(sB + kt3, (char*)Bs[1] + wofs, 512);
    VMW8; PBAR;
    mma16(acc[1][1], af, bf1);
  }

  __syncthreads();  // drain leftover tail DMAs before reusing As as scratch

  const float alpha = 0.044194173824159216f;  // 1/sqrt(512)
  bf16* Sb = S + (long long)b * 2048 * 2048;
  #pragma unroll
  for (int qr = 0; qr < 2; qr++)
    #pragma unroll
    for (int qc = 0; qc < 2; qc++)
      #pragma unroll
      for (int mf = 0; mf < 4; mf++)
        #pragma unroll
        for (int nf = 0; nf < 2; nf++) {
          #pragma unroll
          for (int r = 0; r < 4; r++)
            acc[qr][qc][mf][nf][r] = __expf(acc[qr][qc][mf][nf][r] * alpha);
          const int gcol = col0 + qc * 128 + wn * 32 + nf * 16 + llo;
          const int grow0 = row0 + qr * 128 + wm * 64 + mf * 16 + lhi * 4;
          #pragma unroll
          for (int r = 0; r < 4; r++)
            Sb[(long long)(grow0 + r) * 2048 + gcol] =
                __float2bfloat16(acc[qr][qc][mf][nf][r]);
        }

  float* psum = (float*)As;  // 4 KB scratch (buffers dead, DMAs drained)
  #pragma unroll
  for (int qr = 0; qr < 2; qr++)
    #pragma unroll
    for (int mf = 0; mf < 4; mf++)
      #pragma unroll
      for (int r = 0; r < 4; r++) {
        float p = acc[qr][0][mf][0][r] + acc[qr][0][mf][1][r] +
                  acc[qr][1][mf][0][r] + acc[qr][1][mf][1][r];
        p += __shfl_xor(p, 1, 64);
        p += __shfl_xor(p, 2, 64);
        p += __shfl_xor(p, 4, 64);
        p += __shfl_xor(p, 8, 64);
        if (llo == 0)
          psum[wn * 256 + qr * 128 + wm * 64 + mf * 16 + lhi * 4 + r] = p;
      }
  __syncthreads();
  if (tid < 256) {
    const float v = psum[tid] + psum[256 + tid] + psum[512 + tid] + psum[768 + tid];
    rowsumP[(long long)(b * 8 + coltile) * 2048 + row0 + tid] = v;
  }
}

// ---------------- PV: out[b] = (P[b] V[b]) / rowsum, fp32 out
// 256x128 tile, triple-buffered counted-vmcnt schedule (passed round 4).
// NEW: rinv computed in-kernel from rowsumP (reduce_rowsum launch removed).
#define PV_TILE(c, cs, kstage)                                              \
  do {                                                                      \
    /* Pa: qr=0 */                                                          \
    lda4(As3[c], wm * 64, llo, xk0, xk1, af);                               \
    ldb2(Bs3[c], wn * 32, llo, xk0, xk1, bfr);                              \
    stage_half(sA + (kstage), (char*)As3[cs] + wofs, 2048);                 \
    stage_half(sB + (kstage), (char*)Bs3[cs] + wofs, 2048);                 \
    VMW10; PBAR;                                                            \
    mma16(acc[0], af, bfr);                                                 \
    /* Pb: qr=1 (B frags reused from registers) */                          \
    lda4(As3[c], 128 + wm * 64, llo, xk0, xk1, af);                         \
    stage_half(sA + 128 * 2048 + (kstage), (char*)As3[cs] + 16384 + wofs,   \
               2048);                                                       \
    VMW8; PBAR;                                                             \
    mma16(acc[1], af, bfr);                                                 \
  } while (0)

__global__ __launch_bounds__(512, 2) void gemm_pv(const bf16* __restrict__ S,
                                                  const bf16* __restrict__ vt,
                                                  const float* __restrict__ rowsumP,
                                                  float* __restrict__ out) {
  __shared__ bf16 As3[3][256 * 64];  // 32 KB each
  __shared__ bf16 Bs3[3][128 * 64];  // 16 KB each (total 144 KB)
  const int tid = threadIdx.x;
  const int wave = tid >> 6, lane = tid & 63;
  const int llo = lane & 15, lhi = lane >> 4;
  const int wm = wave >> 2, wn = wave & 3;  // 2 x 4 waves

  const unsigned int lin = blockIdx.x;   // 256 blocks
  const int b = (int)(lin & 7u);         // one batch per XCD
  const unsigned int idx = lin >> 3;     // 0..31
  const int row0 = (int)(idx >> 2) * 256;  // 8 row tiles
  const int col0 = (int)(idx & 3u) * 128;  // 4 col tiles

  const bf16* Ab = S + (long long)b * 2048 * 2048;   // P (unnormalized)
  const bf16* Bb = vt + (long long)b * 512 * 2048;   // V^T: [hid][token]

  const int sr = tid >> 3;
  const int kkofs = ((tid & 7) ^ (sr & 7)) << 3;
  const bf16* sA = Ab + (long long)(row0 + sr) * 2048 + kkofs;
  const bf16* sB = Bb + (long long)(col0 + sr) * 2048 + kkofs;
  const int wofs = wave * 1024;

  const int xk0 = ((lhi ^ (llo & 7)) << 3);
  const int xk1 = (((4 + lhi) ^ (llo & 7)) << 3);

  f32x4 acc[2][4][2] = {};  // [qr][mf][nf] — per-wave output 128x32
  s16x8 af[4][2], bfr[2][2];

  // prologue: tiles 0,1 fully staged = 12 loads, order a0,b,a1 per tile;
  // vmcnt(8) retires a0(0),b(0) -> 8 in flight.
  stage_half(sA, (char*)As3[0] + wofs, 2048);
  stage_half(sB, (char*)Bs3[0] + wofs, 2048);
  stage_half(sA + 128 * 2048, (char*)As3[0] + 16384 + wofs, 2048);
  stage_half(sA + 64, (char*)As3[1] + wofs, 2048);
  stage_half(sB + 64, (char*)Bs3[1] + wofs, 2048);
  stage_half(sA + 128 * 2048 + 64, (char*)As3[1] + 16384 + wofs, 2048);
  VMW8; PBAR;

  for (int j = 0; j < 10; ++j) {       // tiles 3j..3j+2 (0..29); stages 2..31
    const int kb = j * 192;            // element offset of tile 3j
    PV_TILE(0, 2, kb + 128);           // tile 3j   stages tile 3j+2
    PV_TILE(1, 0, kb + 192);           // tile 3j+1 stages tile 3j+3
    PV_TILE(2, 1, kb + 256);           // tile 3j+2 stages tile 3j+4
  }
  // tail: tiles 30 (buf0), 31 (buf1); stages clamp to k=1984 (dups into
  // dead bufs 2 and 0 — never read again).
  PV_TILE(0, 2, 1984);
  PV_TILE(1, 0, 1984);

  asm volatile("s_waitcnt vmcnt(0)" ::: "memory");  // drain clamp dups
  __syncthreads();  // all waves' DMAs landed -> As3[1] safe as scratch

  // fused rinv: rrow[t] = 1 / sum_{ct<8} rowsumP[b][ct][row0+t]
  float* rrow = (float*)As3[1];  // 1 KB scratch (no tail dups land here)
  if (tid < 256) {
    const float* rp = rowsumP + ((long long)b * 8) * 2048 + row0 + tid;
    float s = 0.f;
    #pragma unroll
    for (int t = 0; t < 8; t++) s += rp[t * 2048];
    rrow[tid] = 1.0f / s;
  }
  __syncthreads();

  float* Ob = out + (long long)b * 2048 * 512;
  #pragma unroll
  for (int qr = 0; qr < 2; qr++)
    #pragma unroll
    for (int mf = 0; mf < 4; mf++) {
      const int grow0 = row0 + qr * 128 + wm * 64 + mf * 16 + lhi * 4;
      float iv[4];
      #pragma unroll
      for (int r = 0; r < 4; r++) iv[r] = rrow[grow0 - row0 + r];
      #pragma unroll
      for (int nf = 0; nf < 2; nf++) {
        const int gcol = col0 + wn * 32 + nf * 16 + llo;
        #pragma unroll
        for (int r = 0; r < 4; r++)
          Ob[(long long)(grow0 + r) * 512 + gcol] = acc[qr][mf][nf][r] * iv[r];
      }
    }
}
#undef PV_TILE

extern "C" void kernel_launch(void* const* d_in, const int* in_sizes, int n_in,
                              void* d_out, int out_size, void* d_ws, size_t ws_size,
                              hipStream_t stream) {
  const float* patches = (const float*)d_in[0];
  const float* positions = (const float*)d_in[1];
  const float* Wq = (const float*)d_in[2];
  const float* bq = (const float*)d_in[3];
  const float* Wk = (const float*)d_in[4];
  const float* bk = (const float*)d_in[5];
  const float* Wv = (const float*)d_in[6];
  const float* bv = (const float*)d_in[7];
  float* out = (float*)d_out;

  if (ws_size < 149422080u) return;

  char* ws = (char*)d_ws;
  bf16* Wt = (bf16*)(ws);                    // 3*512*832*2   = 2,555,904
  bf16* xb = (bf16*)(ws + 2555904);          // 16384*832*2   = 27,262,976
  bf16* qk = (bf16*)(ws + 29818880);         // 2*16384*512*2 = 33,554,432 (Q,K)
  bf16* vt = (bf16*)(ws + 63373312);         // 8*512*2048*2  = 16,777,216 (V^T)
  bf16* S  = (bf16*)(ws + 80150528);         // 8*2048*2048*2 = 67,108,864
  float* rowsumP = (float*)(ws + 147324928); // 8*8*2048*4    = 524,288

  prep_x<<<2048, 256, 0, stream>>>(patches, positions, xb);
  prep_w<<<dim3(16, 26, 3), dim3(32, 8), 0, stream>>>(Wq, Wk, Wv, Wt);
  gemm_qkv<<<768, 512, 0, stream>>>(xb, Wt, bq, bk, bv, qk, vt);
  gemm_scores<<<512, 512, 0, stream>>>(qk, S, rowsumP);
  gemm_pv<<<256, 512, 0, stream>>>(S, vt, rowsumP, out);
}

// Round 7
// 248.978 us; speedup vs baseline: 1.0903x; 1.0903x over previous
//
#include <hip/hip_runtime.h>
#include <hip/hip_bf16.h>
#include <math.h>

typedef __hip_bfloat16 bf16;
typedef __attribute__((ext_vector_type(4))) float f32x4;
typedef __attribute__((ext_vector_type(8))) short s16x8;

typedef const __attribute__((address_space(1))) void gvoid_t;
typedef __attribute__((address_space(3))) void lvoid_t;

__device__ __forceinline__ void gload16(const void* g, void* l) {
  // async global->LDS, 16B/lane; LDS dest is wave-uniform base + lane*16
  __builtin_amdgcn_global_load_lds((gvoid_t*)g, (lvoid_t*)l, 16, 0, 0);
}
__device__ __forceinline__ unsigned short f2b(float f) {
  bf16 h = __float2bfloat16(f);
  return *(unsigned short*)&h;
}

// ---------------- prep: x = concat(patches, positions) -> bf16 [16384][832]
__global__ __launch_bounds__(256) void prep_x(const float* __restrict__ patches,
                                              const float* __restrict__ positions,
                                              bf16* __restrict__ xb) {
  const int c = threadIdx.x;
  const bool lo = (c < 192);
  const bool hi = (c >= 192) && (c < 208);
  if (!(lo || hi)) return;
  const int dst = lo ? (c * 4) : (768 + (c - 192) * 4);
  #pragma unroll
  for (int rr = 0; rr < 8; ++rr) {
    const long long row = (long long)blockIdx.x * 8 + rr;
    const float* src = lo ? (patches + row * 768 + c * 4)
                          : (positions + row * 64 + (c - 192) * 4);
    float4 v = *(const float4*)src;
    uint2 w;
    w.x = (unsigned int)f2b(v.x) | ((unsigned int)f2b(v.y) << 16);
    w.y = (unsigned int)f2b(v.z) | ((unsigned int)f2b(v.w) << 16);
    *(uint2*)(xb + row * 832 + dst) = w;
  }
}

// ---------------- prep: Wt[z*512+n][k] = W_z[k][n] bf16 (832x512 -> 512x832)
__global__ __launch_bounds__(256) void prep_w(const float* __restrict__ Wq,
                                              const float* __restrict__ Wk,
                                              const float* __restrict__ Wv,
                                              bf16* __restrict__ Wt) {
  __shared__ float tile[32][33];
  const int z = blockIdx.z;
  const float* W = (z == 0) ? Wq : (z == 1) ? Wk : Wv;
  bf16* T = Wt + (long long)z * 512 * 832;
  const int n0 = blockIdx.x * 32;
  const int k0 = blockIdx.y * 32;
  const int tx = threadIdx.x, ty = threadIdx.y;  // (32,8)
  #pragma unroll
  for (int i = 0; i < 32; i += 8)
    tile[ty + i][tx] = W[(long long)(k0 + ty + i) * 512 + n0 + tx];
  __syncthreads();
  #pragma unroll
  for (int i = 0; i < 32; i += 8)
    T[(long long)(n0 + ty + i) * 832 + k0 + tx] = __float2bfloat16(tile[tx][ty + i]);
}

// ================ shared counted-vmcnt template pieces (HW-verified) ========
#define VMW5  asm volatile("s_waitcnt vmcnt(5)" ::: "memory")
#define VMW8  asm volatile("s_waitcnt vmcnt(8)" ::: "memory")
#define VMW10 asm volatile("s_waitcnt vmcnt(10)" ::: "memory")
#define PBAR do { __builtin_amdgcn_s_barrier(); __builtin_amdgcn_sched_barrier(0); } while (0)

__device__ __forceinline__ void stage_half(const bf16* src, char* lds, int stride) {
  gload16(src, lds);                       // rows r..r+63 of the 128-row half
  gload16(src + 64 * stride, lds + 8192);  // rows r+64..r+127
}
__device__ __forceinline__ void stage_b192(const bf16* src, char* lds) {
  // 192-row B tile, stride 832 (Wt), 3 x 64-row gloads
  gload16(src, lds);
  gload16(src + 64 * 832, lds + 8192);
  gload16(src + 128 * 832, lds + 16384);
}
__device__ __forceinline__ void lda4(const bf16* base, int rowbase, int llo,
                                     int xk0, int xk1, s16x8 af[4][2]) {
  #pragma unroll
  for (int mf = 0; mf < 4; mf++) {
    const bf16* p = base + (rowbase + mf * 16 + llo) * 64;
    af[mf][0] = *(const s16x8*)(p + xk0);
    af[mf][1] = *(const s16x8*)(p + xk1);
  }
}
__device__ __forceinline__ void ldb2(const bf16* base, int rowbase, int llo,
                                     int xk0, int xk1, s16x8 bfr[2][2]) {
  #pragma unroll
  for (int nf = 0; nf < 2; nf++) {
    const bf16* p = base + (rowbase + nf * 16 + llo) * 64;
    bfr[nf][0] = *(const s16x8*)(p + xk0);
    bfr[nf][1] = *(const s16x8*)(p + xk1);
  }
}
__device__ __forceinline__ void ldb3(const bf16* base, int rowbase, int llo,
                                     int xk0, int xk1, s16x8 bfr[3][2]) {
  #pragma unroll
  for (int nf = 0; nf < 3; nf++) {
    const bf16* p = base + (rowbase + nf * 16 + llo) * 64;
    bfr[nf][0] = *(const s16x8*)(p + xk0);
    bfr[nf][1] = *(const s16x8*)(p + xk1);
  }
}
__device__ __forceinline__ void mma16(f32x4 acc[4][2], s16x8 af[4][2],
                                      s16x8 bfr[2][2]) {
  __builtin_amdgcn_s_setprio(1);
  #pragma unroll
  for (int mf = 0; mf < 4; mf++)
    #pragma unroll
    for (int nf = 0; nf < 2; nf++) {
      acc[mf][nf] = __builtin_amdgcn_mfma_f32_16x16x32_bf16(
          af[mf][0], bfr[nf][0], acc[mf][nf], 0, 0, 0);
      acc[mf][nf] = __builtin_amdgcn_mfma_f32_16x16x32_bf16(
          af[mf][1], bfr[nf][1], acc[mf][nf], 0, 0, 0);
    }
  __builtin_amdgcn_s_setprio(0);
}
__device__ __forceinline__ void mma24(f32x4 acc[4][3], s16x8 af[4][2],
                                      s16x8 bfr[3][2]) {
  __builtin_amdgcn_s_setprio(1);
  #pragma unroll
  for (int mf = 0; mf < 4; mf++)
    #pragma unroll
    for (int nf = 0; nf < 3; nf++) {
      acc[mf][nf] = __builtin_amdgcn_mfma_f32_16x16x32_bf16(
          af[mf][0], bfr[nf][0], acc[mf][nf], 0, 0, 0);
      acc[mf][nf] = __builtin_amdgcn_mfma_f32_16x16x32_bf16(
          af[mf][1], bfr[nf][1], acc[mf][nf], 0, 0, 0);
    }
  __builtin_amdgcn_s_setprio(0);
}

// ---------------- fused QKV projection: [16384,832] x [1536,832]^T
// R5 version VERBATIM (best measured: 56.5 us, MfmaUtil 28%, FETCH 33.5 MB).
// 256x192 tile -> 64x8 = 512 blocks = 2 exact rounds. A double-buffered,
// B triple-buffered, uniform vmcnt(5).
#define QKV_TILE(abuf, bbuf, bstage, ka1, kb2)                               \
  do {                                                                       \
    /* Pa: qr=0 */                                                           \
    lda4(As2[abuf], wm * 64, llo, xk0, xk1, af);                             \
    ldb3(Bs3[bbuf], wn * 48, llo, xk0, xk1, bfr);                            \
    stage_half(sA + (ka1), (char*)As2[(abuf) ^ 1] + wofs, 832);              \
    stage_b192(sB + (kb2), (char*)Bs3[bstage] + wofs);                       \
    VMW5; PBAR;                                                              \
    mma24(acc[0], af, bfr);                                                  \
    /* Pb: qr=1 (B frags reused from registers) */                           \
    lda4(As2[abuf], 128 + wm * 64, llo, xk0, xk1, af);                       \
    stage_half(sA + 128 * 832 + (ka1), (char*)As2[(abuf) ^ 1] + 16384 + wofs,\
               832);                                                         \
    VMW5; PBAR;                                                              \
    mma24(acc[1], af, bfr);                                                  \
  } while (0)

__global__ __launch_bounds__(512, 2) void gemm_qkv(
    const bf16* __restrict__ xb, const bf16* __restrict__ Wt,
    const float* __restrict__ bq, const float* __restrict__ bk,
    const float* __restrict__ bv,
    bf16* __restrict__ qk, bf16* __restrict__ vt) {
  __shared__ bf16 As2[2][256 * 64];  // 32 KB each (a0 rows 0-127, a1 128-255)
  __shared__ bf16 Bs3[3][192 * 64];  // 24 KB each
  const int tid = threadIdx.x;
  const int wave = tid >> 6, lane = tid & 63;
  const int llo = lane & 15, lhi = lane >> 4;
  const int wm = wave >> 2, wn = wave & 3;  // 2 x 4 waves

  const unsigned int lin = blockIdx.x;      // 512 blocks (512%8==0, bijective)
  const unsigned int xcd = lin & 7u, idx = lin >> 3;  // idx 0..63
  const unsigned int g = xcd * 64u + idx;   // each XCD: 8 consecutive bm rows
  const int bm_t = (int)(g >> 3);           // 0..63
  const int bn_t = (int)(g & 7u);           // 0..7
  const int row0 = bm_t * 256;
  const int col0 = bn_t * 192;

  // staging: pre-swizzled global source, linear LDS dest (rule 21 pair)
  const int sr = tid >> 3;                        // 0..63
  const int kkofs = ((tid & 7) ^ (sr & 7)) << 3;  // element offset
  const bf16* sA = xb + (long long)(row0 + sr) * 832 + kkofs;
  const bf16* sB = Wt + (long long)(col0 + sr) * 832 + kkofs;
  const int wofs = wave * 1024;

  // read-side swizzled chunk offsets (elements), k0=0 and k0=32
  const int xk0 = ((lhi ^ (llo & 7)) << 3);
  const int xk1 = (((4 + lhi) ^ (llo & 7)) << 3);

  f32x4 acc[2][4][3] = {};  // [qr][mf][nf] — per-wave output 128x48
  s16x8 af[4][2], bfr[3][2];

  // prologue: a0(0) 2, b(0) 3, a1(0) 2, b(1) 3 = 10 loads;
  // vmcnt(5) retires a0(0)+b(0) (Pa(0)'s reads); invariant established.
  stage_half(sA, (char*)As2[0] + wofs, 832);
  stage_b192(sB, (char*)Bs3[0] + wofs);
  stage_half(sA + 128 * 832, (char*)As2[0] + 16384 + wofs, 832);
  stage_b192(sB + 64, (char*)Bs3[1] + wofs);
  VMW5; PBAR;

  for (int jj = 0; jj < 2; ++jj) {  // tiles 6jj .. 6jj+5
    const int u0 = jj * 6;
    QKV_TILE(0, 0, 2, (u0 + 1) * 64, (u0 + 2) * 64);
    QKV_TILE(1, 1, 0, (u0 + 2) * 64, (u0 + 3) * 64);
    QKV_TILE(0, 2, 1, (u0 + 3) * 64, (u0 + 4) * 64);
    QKV_TILE(1, 0, 2, (u0 + 4) * 64, (u0 + 5) * 64);
    QKV_TILE(0, 1, 0, (u0 + 5) * 64, (u0 + 6) * 64);
    QKV_TILE(1, 2, 1, (u0 + 6) * 64, ((u0 + 7) <= 12 ? (u0 + 7) * 64 : 768));
  }
  QKV_TILE(0, 0, 2, 768, 768);  // tile 12; clamped stages -> dead buffers

  asm volatile("s_waitcnt vmcnt(0)" ::: "memory");  // drain clamp dups

  // epilogue: C/D layout col=lane&15, row=(lane>>4)*4+reg.
  // 192-col tiles straddle the z (Q/K/V) boundary; z is uniform per 16-col
  // fragment (frag base and 512 both 16-aligned).
  #pragma unroll
  for (int qr = 0; qr < 2; qr++)
    #pragma unroll
    for (int mf = 0; mf < 4; mf++)
      #pragma unroll
      for (int nf = 0; nf < 3; nf++) {
        const int c = col0 + wn * 48 + nf * 16 + llo;
        const int z = c >> 9, cc = c & 511;
        const int grow0 = row0 + qr * 128 + wm * 64 + mf * 16 + lhi * 4;
        if (z < 2) {
          const float bb = (z ? bk : bq)[cc];
          bf16* outp = qk + (long long)z * 16384 * 512;
          #pragma unroll
          for (int r = 0; r < 4; r++)
            outp[(long long)(grow0 + r) * 512 + cc] =
                __float2bfloat16(acc[qr][mf][nf][r] + bb);
        } else {
          const int b = grow0 >> 11, j = grow0 & 2047;
          const float bb = bv[cc];
          uint2 w;
          w.x = (unsigned int)f2b(acc[qr][mf][nf][0] + bb) |
                ((unsigned int)f2b(acc[qr][mf][nf][1] + bb) << 16);
          w.y = (unsigned int)f2b(acc[qr][mf][nf][2] + bb) |
                ((unsigned int)f2b(acc[qr][mf][nf][3] + bb) << 16);
          *(uint2*)(vt + (long long)b * 512 * 2048 + (long long)cc * 2048 + j) = w;
        }
      }
}
#undef QKV_TILE

// ---------------- scores+exp: 256x256 tile, 8 waves, 8-phase counted-vmcnt
// (passed rounds 1-6; unchanged)
__global__ __launch_bounds__(512, 2) void gemm_scores(const bf16* __restrict__ qk,
                                                      bf16* __restrict__ S,
                                                      float* __restrict__ rowsumP) {
  __shared__ bf16 As[2][256 * 64];
  __shared__ bf16 Bs[2][256 * 64];
  const int tid = threadIdx.x;
  const int wave = tid >> 6, lane = tid & 63;
  const int llo = lane & 15, lhi = lane >> 4;
  const int wm = wave >> 2, wn = wave & 3;  // 2 x 4 waves

  const unsigned int lin = blockIdx.x;  // 512 blocks
  const int b = (int)(lin & 7u);        // one batch per XCD (Q+K = 4MB = L2)
  const unsigned int idx = lin >> 3;    // 0..63
  const int row0 = (int)(idx >> 3) * 256;
  const int coltile = (int)(idx & 7u);
  const int col0 = coltile * 256;

  const bf16* Ab = qk + (long long)b * 2048 * 512;                           // Q
  const bf16* Bb = qk + (long long)16384 * 512 + (long long)b * 2048 * 512;  // K

  const int sr = tid >> 3;
  const int kkofs = ((tid & 7) ^ (sr & 7)) << 3;
  const bf16* sA = Ab + (long long)(row0 + sr) * 512 + kkofs;
  const bf16* sB = Bb + (long long)(col0 + sr) * 512 + kkofs;
  const int wofs = wave * 1024;

  const int xk0 = ((lhi ^ (llo & 7)) << 3);
  const int xk1 = (((4 + lhi) ^ (llo & 7)) << 3);

  f32x4 acc[2][2][4][2] = {};   // [qr][qc][mf][nf]
  s16x8 af[4][2], bf0[2][2], bf1[2][2];

  stage_half(sA, (char*)As[0] + wofs, 512);
  stage_half(sB, (char*)Bs[0] + wofs, 512);
  stage_half(sB + 128 * 512, (char*)Bs[0] + 16384 + wofs, 512);
  stage_half(sA + 128 * 512, (char*)As[0] + 16384 + wofs, 512);
  stage_half(sA + 64, (char*)As[1] + wofs, 512);
  stage_half(sB + 64, (char*)Bs[1] + wofs, 512);
  VMW8; PBAR;

  for (int i = 0; i < 4; ++i) {   // 2 K-tiles per iteration, K=512 -> 8 tiles
    const int kt1 = (2 * i + 1) * 64;
    const int kt2 = (2 * i + 2 < 8) ? (2 * i + 2) * 64 : 448;  // clamp tail
    const int kt3 = (2 * i + 3 < 8) ? (2 * i + 3) * 64 : 448;
    // P1
    lda4(As[0], wm * 64, llo, xk0, xk1, af);
    ldb2(Bs[0], wn * 32, llo, xk0, xk1, bf0);
    stage_half(sB + 128 * 512 + kt1, (char*)Bs[1] + 16384 + wofs, 512);
    VMW8; PBAR;
    mma16(acc[0][0], af, bf0);
    // P2
    ldb2(Bs[0], 128 + wn * 32, llo, xk0, xk1, bf1);
    stage_half(sA + 128 * 512 + kt1, (char*)As[1] + 16384 + wofs, 512);
    VMW8; PBAR;
    mma16(acc[0][1], af, bf1);
    // P3
    lda4(As[0], 128 + wm * 64, llo, xk0, xk1, af);
    stage_half(sA + kt2, (char*)As[0] + wofs, 512);
    PBAR;
    mma16(acc[1][0], af, bf0);
    // P4
    stage_half(sB + kt2, (char*)Bs[0] + wofs, 512);
    VMW8; PBAR;
    mma16(acc[1][1], af, bf1);
    // P5
    lda4(As[1], wm * 64, llo, xk0, xk1, af);
    ldb2(Bs[1], wn * 32, llo, xk0, xk1, bf0);
    stage_half(sB + 128 * 512 + kt2, (char*)Bs[0] + 16384 + wofs, 512);
    VMW8; PBAR;
    mma16(acc[0][0], af, bf0);
    // P6
    ldb2(Bs[1], 128 + wn * 32, llo, xk0, xk1, bf1);
    stage_half(sA + 128 * 512 + kt2, (char*)As[0] + 16384 + wofs, 512);
    VMW8; PBAR;
    mma16(acc[0][1], af, bf1);
    // P7
    lda4(As[1], 128 + wm * 64, llo, xk0, xk1, af);
    stage_half(sA + kt3, (char*)As[1] + wofs, 512);
    PBAR;
    mma16(acc[1][0], af, bf0);
    // P8
    stage_half(sB + kt3, (char*)Bs[1] + wofs, 512);
    VMW8; PBAR;
    mma16(acc[1][1], af, bf1);
  }

  __syncthreads();  // drain leftover tail DMAs before reusing As as scratch

  const float alpha = 0.044194173824159216f;  // 1/sqrt(512)
  bf16* Sb = S + (long long)b * 2048 * 2048;
  #pragma unroll
  for (int qr = 0; qr < 2; qr++)
    #pragma unroll
    for (int qc = 0; qc < 2; qc++)
      #pragma unroll
      for (int mf = 0; mf < 4; mf++)
        #pragma unroll
        for (int nf = 0; nf < 2; nf++) {
          #pragma unroll
          for (int r = 0; r < 4; r++)
            acc[qr][qc][mf][nf][r] = __expf(acc[qr][qc][mf][nf][r] * alpha);
          const int gcol = col0 + qc * 128 + wn * 32 + nf * 16 + llo;
          const int grow0 = row0 + qr * 128 + wm * 64 + mf * 16 + lhi * 4;
          #pragma unroll
          for (int r = 0; r < 4; r++)
            Sb[(long long)(grow0 + r) * 2048 + gcol] =
                __float2bfloat16(acc[qr][qc][mf][nf][r]);
        }

  float* psum = (float*)As;  // 4 KB scratch (buffers dead, DMAs drained)
  #pragma unroll
  for (int qr = 0; qr < 2; qr++)
    #pragma unroll
    for (int mf = 0; mf < 4; mf++)
      #pragma unroll
      for (int r = 0; r < 4; r++) {
        float p = acc[qr][0][mf][0][r] + acc[qr][0][mf][1][r] +
                  acc[qr][1][mf][0][r] + acc[qr][1][mf][1][r];
        p += __shfl_xor(p, 1, 64);
        p += __shfl_xor(p, 2, 64);
        p += __shfl_xor(p, 4, 64);
        p += __shfl_xor(p, 8, 64);
        if (llo == 0)
          psum[wn * 256 + qr * 128 + wm * 64 + mf * 16 + lhi * 4 + r] = p;
      }
  __syncthreads();
  if (tid < 256) {
    const float v = psum[tid] + psum[256 + tid] + psum[512 + tid] + psum[768 + tid];
    rowsumP[(long long)(b * 8 + coltile) * 2048 + row0 + tid] = v;
  }
}

// ---------------- PV: out[b] = (P[b] V[b]) / rowsum, fp32 out
// 256x128 tile, triple-buffered counted-vmcnt schedule (passed R4/R6),
// rinv computed in-kernel from rowsumP (fused reduce, passed R6).
#define PV_TILE(c, cs, kstage)                                              \
  do {                                                                      \
    /* Pa: qr=0 */                                                          \
    lda4(As3[c], wm * 64, llo, xk0, xk1, af);                               \
    ldb2(Bs3[c], wn * 32, llo, xk0, xk1, bfr);                              \
    stage_half(sA + (kstage), (char*)As3[cs] + wofs, 2048);                 \
    stage_half(sB + (kstage), (char*)Bs3[cs] + wofs, 2048);                 \
    VMW10; PBAR;                                                            \
    mma16(acc[0], af, bfr);                                                 \
    /* Pb: qr=1 (B frags reused from registers) */                          \
    lda4(As3[c], 128 + wm * 64, llo, xk0, xk1, af);                         \
    stage_half(sA + 128 * 2048 + (kstage), (char*)As3[cs] + 16384 + wofs,   \
               2048);                                                       \
    VMW8; PBAR;                                                             \
    mma16(acc[1], af, bfr);                                                 \
  } while (0)

__global__ __launch_bounds__(512, 2) void gemm_pv(const bf16* __restrict__ S,
                                                  const bf16* __restrict__ vt,
                                                  const float* __restrict__ rowsumP,
                                                  float* __restrict__ out) {
  __shared__ bf16 As3[3][256 * 64];  // 32 KB each
  __shared__ bf16 Bs3[3][128 * 64];  // 16 KB each (total 144 KB)
  const int tid = threadIdx.x;
  const int wave = tid >> 6, lane = tid & 63;
  const int llo = lane & 15, lhi = lane >> 4;
  const int wm = wave >> 2, wn = wave & 3;  // 2 x 4 waves

  const unsigned int lin = blockIdx.x;   // 256 blocks
  const int b = (int)(lin & 7u);         // one batch per XCD
  const unsigned int idx = lin >> 3;     // 0..31
  const int row0 = (int)(idx >> 2) * 256;  // 8 row tiles
  const int col0 = (int)(idx & 3u) * 128;  // 4 col tiles

  const bf16* Ab = S + (long long)b * 2048 * 2048;   // P (unnormalized)
  const bf16* Bb = vt + (long long)b * 512 * 2048;   // V^T: [hid][token]

  const int sr = tid >> 3;
  const int kkofs = ((tid & 7) ^ (sr & 7)) << 3;
  const bf16* sA = Ab + (long long)(row0 + sr) * 2048 + kkofs;
  const bf16* sB = Bb + (long long)(col0 + sr) * 2048 + kkofs;
  const int wofs = wave * 1024;

  const int xk0 = ((lhi ^ (llo & 7)) << 3);
  const int xk1 = (((4 + lhi) ^ (llo & 7)) << 3);

  f32x4 acc[2][4][2] = {};  // [qr][mf][nf] — per-wave output 128x32
  s16x8 af[4][2], bfr[2][2];

  // prologue: tiles 0,1 fully staged = 12 loads, order a0,b,a1 per tile;
  // vmcnt(8) retires a0(0),b(0) -> 8 in flight.
  stage_half(sA, (char*)As3[0] + wofs, 2048);
  stage_half(sB, (char*)Bs3[0] + wofs, 2048);
  stage_half(sA + 128 * 2048, (char*)As3[0] + 16384 + wofs, 2048);
  stage_half(sA + 64, (char*)As3[1] + wofs, 2048);
  stage_half(sB + 64, (char*)Bs3[1] + wofs, 2048);
  stage_half(sA + 128 * 2048 + 64, (char*)As3[1] + 16384 + wofs, 2048);
  VMW8; PBAR;

  for (int j = 0; j < 10; ++j) {       // tiles 3j..3j+2 (0..29); stages 2..31
    const int kb = j * 192;            // element offset of tile 3j
    PV_TILE(0, 2, kb + 128);           // tile 3j   stages tile 3j+2
    PV_TILE(1, 0, kb + 192);           // tile 3j+1 stages tile 3j+3
    PV_TILE(2, 1, kb + 256);           // tile 3j+2 stages tile 3j+4
  }
  // tail: tiles 30 (buf0), 31 (buf1); stages clamp to k=1984 (dups into
  // dead bufs 2 and 0 — never read again).
  PV_TILE(0, 2, 1984);
  PV_TILE(1, 0, 1984);

  asm volatile("s_waitcnt vmcnt(0)" ::: "memory");  // drain clamp dups
  __syncthreads();  // all waves' DMAs landed -> As3[1] safe as scratch

  // fused rinv: rrow[t] = 1 / sum_{ct<8} rowsumP[b][ct][row0+t]
  float* rrow = (float*)As3[1];  // 1 KB scratch (no tail dups land here)
  if (tid < 256) {
    const float* rp = rowsumP + ((long long)b * 8) * 2048 + row0 + tid;
    float s = 0.f;
    #pragma unroll
    for (int t = 0; t < 8; t++) s += rp[t * 2048];
    rrow[tid] = 1.0f / s;
  }
  __syncthreads();

  float* Ob = out + (long long)b * 2048 * 512;
  #pragma unroll
  for (int qr = 0; qr < 2; qr++)
    #pragma unroll
    for (int mf = 0; mf < 4; mf++) {
      const int grow0 = row0 + qr * 128 + wm * 64 + mf * 16 + lhi * 4;
      float iv[4];
      #pragma unroll
      for (int r = 0; r < 4; r++) iv[r] = rrow[grow0 - row0 + r];
      #pragma unroll
      for (int nf = 0; nf < 2; nf++) {
        const int gcol = col0 + wn * 32 + nf * 16 + llo;
        #pragma unroll
        for (int r = 0; r < 4; r++)
          Ob[(long long)(grow0 + r) * 512 + gcol] = acc[qr][mf][nf][r] * iv[r];
      }
    }
}
#undef PV_TILE

extern "C" void kernel_launch(void* const* d_in, const int* in_sizes, int n_in,
                              void* d_out, int out_size, void* d_ws, size_t ws_size,
                              hipStream_t stream) {
  const float* patches = (const float*)d_in[0];
  const float* positions = (const float*)d_in[1];
  const float* Wq = (const float*)d_in[2];
  const float* bq = (const float*)d_in[3];
  const float* Wk = (const float*)d_in[4];
  const float* bk = (const float*)d_in[5];
  const float* Wv = (const float*)d_in[6];
  const float* bv = (const float*)d_in[7];
  float* out = (float*)d_out;

  if (ws_size < 149422080u) return;

  char* ws = (char*)d_ws;
  bf16* Wt = (bf16*)(ws);                    // 3*512*832*2   = 2,555,904
  bf16* xb = (bf16*)(ws + 2555904);          // 16384*832*2   = 27,262,976
  bf16* qk = (bf16*)(ws + 29818880);         // 2*16384*512*2 = 33,554,432 (Q,K)
  bf16* vt = (bf16*)(ws + 63373312);         // 8*512*2048*2  = 16,777,216 (V^T)
  bf16* S  = (bf16*)(ws + 80150528);         // 8*2048*2048*2 = 67,108,864
  float* rowsumP = (float*)(ws + 147324928); // 8*8*2048*4    = 524,288

  prep_x<<<2048, 256, 0, stream>>>(patches, positions, xb);
  prep_w<<<dim3(16, 26, 3), dim3(32, 8), 0, stream>>>(Wq, Wk, Wv, Wt);
  gemm_qkv<<<512, 512, 0, stream>>>(xb, Wt, bq, bk, bv, qk, vt);
  gemm_scores<<<512, 512, 0, stream>>>(qk, S, rowsumP);
  gemm_pv<<<256, 512, 0, stream>>>(S, vt, rowsumP, out);
}